// Round 1
// baseline (4219.303 us; speedup 1.0000x reference)
//
#include <hip/hip_runtime.h>

// GCN 2-layer on MI355X.
// Factorization: agg[i] = dinv[i] * (sum_{e:dst=i} hs[src_e] + hs[i]),
// hs[j] = (x@W)[j] * dinv[j]. Self-loop folded into the node epilogue.
//
// ws layout (floats): deg/dinv [0,N) | hs1 [N,9N) | acc1 [9N,17N)
//                     | hs2 [17N,21N) | acc2 [21N,25N)   (20 MB total)

__global__ __launch_bounds__(256) void deg_kernel(
    const int* __restrict__ dst, float* __restrict__ deg, int E) {
    int e = blockIdx.x * blockDim.x + threadIdx.x;
    if (e < E) atomicAdd(&deg[dst[e]], 1.0f);
}

__global__ __launch_bounds__(256) void node1_kernel(
    const float* __restrict__ x, float* __restrict__ deg_dinv,
    const float* __restrict__ W1, float* __restrict__ hs1, int n) {
    int i = blockIdx.x * blockDim.x + threadIdx.x;
    if (i >= n) return;
    // self-loop adds +1 to degree; deg >= 1 so rsqrt is safe
    float d = rsqrtf(deg_dinv[i] + 1.0f);
    deg_dinv[i] = d;  // overwrite deg with dinv in place
    float x0 = x[2 * i], x1 = x[2 * i + 1];
    float4 o0, o1;
    o0.x = (x0 * W1[0] + x1 * W1[8])  * d;
    o0.y = (x0 * W1[1] + x1 * W1[9])  * d;
    o0.z = (x0 * W1[2] + x1 * W1[10]) * d;
    o0.w = (x0 * W1[3] + x1 * W1[11]) * d;
    o1.x = (x0 * W1[4] + x1 * W1[12]) * d;
    o1.y = (x0 * W1[5] + x1 * W1[13]) * d;
    o1.z = (x0 * W1[6] + x1 * W1[14]) * d;
    o1.w = (x0 * W1[7] + x1 * W1[15]) * d;
    float4* out = (float4*)(hs1 + 8 * i);
    out[0] = o0;
    out[1] = o1;
}

__global__ __launch_bounds__(256) void scatter1_kernel(
    const int* __restrict__ src, const int* __restrict__ dst,
    const float* __restrict__ hs1, float* __restrict__ acc1, int E) {
    int e = blockIdx.x * blockDim.x + threadIdx.x;
    if (e >= E) return;
    int s = src[e], d = dst[e];
    const float4* hp = (const float4*)(hs1 + 8 * s);
    float4 a = hp[0], b = hp[1];
    float* out = acc1 + 8 * d;
    atomicAdd(out + 0, a.x); atomicAdd(out + 1, a.y);
    atomicAdd(out + 2, a.z); atomicAdd(out + 3, a.w);
    atomicAdd(out + 4, b.x); atomicAdd(out + 5, b.y);
    atomicAdd(out + 6, b.z); atomicAdd(out + 7, b.w);
}

__global__ __launch_bounds__(256) void node2_kernel(
    const float* __restrict__ dinv, const float* __restrict__ hs1,
    const float* __restrict__ acc1, const float* __restrict__ b1,
    const float* __restrict__ W2, float* __restrict__ hs2, int n) {
    int i = blockIdx.x * blockDim.x + threadIdx.x;
    if (i >= n) return;
    float d = dinv[i];
    const float4* ap = (const float4*)(acc1 + 8 * i);
    const float4* hp = (const float4*)(hs1 + 8 * i);
    float4 a0 = ap[0], a1 = ap[1], h0 = hp[0], h1 = hp[1];
    float h[8];
    h[0] = fmaxf(d * (a0.x + h0.x) + b1[0], 0.0f);
    h[1] = fmaxf(d * (a0.y + h0.y) + b1[1], 0.0f);
    h[2] = fmaxf(d * (a0.z + h0.z) + b1[2], 0.0f);
    h[3] = fmaxf(d * (a0.w + h0.w) + b1[3], 0.0f);
    h[4] = fmaxf(d * (a1.x + h1.x) + b1[4], 0.0f);
    h[5] = fmaxf(d * (a1.y + h1.y) + b1[5], 0.0f);
    h[6] = fmaxf(d * (a1.z + h1.z) + b1[6], 0.0f);
    h[7] = fmaxf(d * (a1.w + h1.w) + b1[7], 0.0f);
    float4 o;
    float oc[4];
    #pragma unroll
    for (int c = 0; c < 4; c++) {
        float acc = 0.0f;
        #pragma unroll
        for (int f = 0; f < 8; f++) acc += h[f] * W2[4 * f + c];
        oc[c] = acc * d;
    }
    o.x = oc[0]; o.y = oc[1]; o.z = oc[2]; o.w = oc[3];
    *(float4*)(hs2 + 4 * i) = o;
}

__global__ __launch_bounds__(256) void scatter2_kernel(
    const int* __restrict__ src, const int* __restrict__ dst,
    const float* __restrict__ hs2, float* __restrict__ acc2, int E) {
    int e = blockIdx.x * blockDim.x + threadIdx.x;
    if (e >= E) return;
    int s = src[e], d = dst[e];
    float4 a = *(const float4*)(hs2 + 4 * s);
    float* out = acc2 + 4 * d;
    atomicAdd(out + 0, a.x); atomicAdd(out + 1, a.y);
    atomicAdd(out + 2, a.z); atomicAdd(out + 3, a.w);
}

__global__ __launch_bounds__(256) void node3_kernel(
    const float* __restrict__ dinv, const float* __restrict__ hs2,
    const float* __restrict__ acc2, const float* __restrict__ b2,
    float* __restrict__ out, int n) {
    int i = blockIdx.x * blockDim.x + threadIdx.x;
    if (i >= n) return;
    float d = dinv[i];
    float4 a = *(const float4*)(acc2 + 4 * i);
    float4 h = *(const float4*)(hs2 + 4 * i);
    float4 o;
    o.x = d * (a.x + h.x) + b2[0];
    o.y = d * (a.y + h.y) + b2[1];
    o.z = d * (a.z + h.z) + b2[2];
    o.w = d * (a.w + h.w) + b2[3];
    *(float4*)(out + 4 * i) = o;
}

extern "C" void kernel_launch(void* const* d_in, const int* in_sizes, int n_in,
                              void* d_out, int out_size, void* d_ws, size_t ws_size,
                              hipStream_t stream) {
    const float* x   = (const float*)d_in[0];
    const int*   ei  = (const int*)d_in[1];
    const float* W1  = (const float*)d_in[2];
    const float* b1  = (const float*)d_in[3];
    const float* W2  = (const float*)d_in[4];
    const float* b2  = (const float*)d_in[5];
    float* out = (float*)d_out;

    const int n = in_sizes[0] / 2;      // x is [N,2]
    const int E = in_sizes[1] / 2;      // edge_index is [2,E]
    const int* src = ei;
    const int* dst = ei + E;

    float* ws   = (float*)d_ws;
    float* deg  = ws;                   // N   (becomes dinv)
    float* hs1  = ws + n;               // 8N
    float* acc1 = ws + 9 * (size_t)n;   // 8N
    float* hs2  = ws + 17 * (size_t)n;  // 4N
    float* acc2 = ws + 21 * (size_t)n;  // 4N

    // zero deg + acc1 + acc2 (ws is poisoned 0xAA before every timed call)
    hipMemsetAsync(deg,  0, (size_t)n * sizeof(float), stream);
    hipMemsetAsync(acc1, 0, (size_t)n * 8 * sizeof(float), stream);
    hipMemsetAsync(acc2, 0, (size_t)n * 4 * sizeof(float), stream);

    const int TB = 256;
    const int gE = (E + TB - 1) / TB;
    const int gN = (n + TB - 1) / TB;

    deg_kernel<<<gE, TB, 0, stream>>>(dst, deg, E);
    node1_kernel<<<gN, TB, 0, stream>>>(x, deg, W1, hs1, n);
    scatter1_kernel<<<gE, TB, 0, stream>>>(src, dst, hs1, acc1, E);
    node2_kernel<<<gN, TB, 0, stream>>>(deg, hs1, acc1, b1, W2, hs2, n);
    scatter2_kernel<<<gE, TB, 0, stream>>>(src, dst, hs2, acc2, E);
    node3_kernel<<<gN, TB, 0, stream>>>(deg, hs2, acc2, b2, out, n);
}

// Round 2
// 1092.197 us; speedup vs baseline: 3.8631x; 3.8631x over previous
//
#include <hip/hip_runtime.h>

// GCN 2-layer on MI355X — Round 2: CSR counting-sort + gather (no float atomics).
//
// agg[i] = dinv[i] * (sum_{e:dst=i} hs[src_e] + hs[i]),  hs[j] = (x@W)[j]*dinv[j]
//
// Pipeline: memset deg -> int histogram -> 3-kernel scan -> placement (dst-sorted
// src list) -> node1 (dinv,hs1) -> gather1 -> node2 (relu+W2,hs2) -> gather2(out).
//
// ws layout (4B elems), n=200000 (divisible by 4, keeps 16B alignment):
//   deg       int[n]      @ 0
//   rowptr    int[n+4]    @ n
//   cursor    int[n]      @ 2n+4
//   partials  int[256]    @ 3n+4
//   dinv      float[n]    @ 3n+260
//   hs1       float[8n]   @ 4n+260
//   agg1      float[8n]   @ 12n+260
//   hs2       float[4n]   @ 20n+260
//   srcsorted int[E]      @ 24n+260        total ~44.8 MB

__global__ __launch_bounds__(256) void hist_kernel(
    const int* __restrict__ dst, int* __restrict__ deg, int E) {
    int e = blockIdx.x * blockDim.x + threadIdx.x;
    if (e < E) atomicAdd(&deg[dst[e]], 1);
}

// Block scans 1024 elements (4/thread); writes within-block exclusive prefix
// to rowptr and the block total to partials[blockIdx.x].
__global__ __launch_bounds__(256) void scan1_kernel(
    const int* __restrict__ deg, int* __restrict__ rowptr,
    int* __restrict__ partials, int n) {
    __shared__ int sdata[256];
    int tid = threadIdx.x;
    int base = blockIdx.x * 1024 + tid * 4;
    int v[4];
    int s = 0;
    #pragma unroll
    for (int k = 0; k < 4; k++) {
        int idx = base + k;
        v[k] = (idx < n) ? deg[idx] : 0;
        s += v[k];
    }
    int x = s;
    sdata[tid] = x;
    __syncthreads();
    for (int off = 1; off < 256; off <<= 1) {
        int t = (tid >= off) ? sdata[tid - off] : 0;
        __syncthreads();
        x += t;
        sdata[tid] = x;
        __syncthreads();
    }
    int run = x - s;  // exclusive prefix of this thread's 4-chunk
    #pragma unroll
    for (int k = 0; k < 4; k++) {
        int idx = base + k;
        if (idx < n) rowptr[idx] = run;
        run += v[k];
    }
    if (tid == 255) partials[blockIdx.x] = x;  // block total
}

// Single block: exclusive scan of block partials (nb <= 256).
__global__ __launch_bounds__(256) void scan2_kernel(int* partials, int nb) {
    __shared__ int sdata[256];
    int tid = threadIdx.x;
    int v = (tid < nb) ? partials[tid] : 0;
    int x = v;
    sdata[tid] = x;
    __syncthreads();
    for (int off = 1; off < 256; off <<= 1) {
        int t = (tid >= off) ? sdata[tid - off] : 0;
        __syncthreads();
        x += t;
        sdata[tid] = x;
        __syncthreads();
    }
    if (tid < nb) partials[tid] = x - v;
}

// Add block offsets; produce final rowptr and a working copy (cursor).
__global__ __launch_bounds__(256) void scan3_kernel(
    int* __restrict__ rowptr, int* __restrict__ cursor,
    const int* __restrict__ partials, int n, int E) {
    int i = blockIdx.x * blockDim.x + threadIdx.x;
    if (i < n) {
        int r = rowptr[i] + partials[i >> 10];
        rowptr[i] = r;
        cursor[i] = r;
    }
    if (i == 0) rowptr[n] = E;
}

// Counting-sort placement: srcsorted gets src ids grouped by dst.
// After this kernel, cursor[i] == row end for node i.
__global__ __launch_bounds__(256) void place_kernel(
    const int* __restrict__ src, const int* __restrict__ dst,
    int* __restrict__ cursor, int* __restrict__ srcsorted, int E) {
    int e = blockIdx.x * blockDim.x + threadIdx.x;
    if (e < E) {
        int p = atomicAdd(&cursor[dst[e]], 1);
        srcsorted[p] = src[e];
    }
}

__global__ __launch_bounds__(256) void node1_kernel(
    const float* __restrict__ x, const int* __restrict__ deg,
    float* __restrict__ dinv, const float* __restrict__ W1,
    float* __restrict__ hs1, int n) {
    int i = blockIdx.x * blockDim.x + threadIdx.x;
    if (i >= n) return;
    float d = rsqrtf((float)deg[i] + 1.0f);  // +1 for self-loop
    dinv[i] = d;
    float x0 = x[2 * i], x1 = x[2 * i + 1];
    float4 o0, o1;
    o0.x = (x0 * W1[0] + x1 * W1[8])  * d;
    o0.y = (x0 * W1[1] + x1 * W1[9])  * d;
    o0.z = (x0 * W1[2] + x1 * W1[10]) * d;
    o0.w = (x0 * W1[3] + x1 * W1[11]) * d;
    o1.x = (x0 * W1[4] + x1 * W1[12]) * d;
    o1.y = (x0 * W1[5] + x1 * W1[13]) * d;
    o1.z = (x0 * W1[6] + x1 * W1[14]) * d;
    o1.w = (x0 * W1[7] + x1 * W1[15]) * d;
    float4* outp = (float4*)(hs1 + 8 * i);
    outp[0] = o0;
    outp[1] = o1;
}

// Thread = (node, feature f in 0..7). Lanes f=0..7 of one node read 8
// consecutive floats of hs1[src] -> coalesced 32B groups; srcsorted[p] is
// broadcast across those 8 lanes.
__global__ __launch_bounds__(256) void gather1_kernel(
    const int* __restrict__ rowptr, const int* __restrict__ cursor,
    const int* __restrict__ srcsorted, const float* __restrict__ hs1,
    float* __restrict__ agg1, int n) {
    int t = blockIdx.x * blockDim.x + threadIdx.x;
    int i = t >> 3, f = t & 7;
    if (i >= n) return;
    int p0 = rowptr[i], p1 = cursor[i];
    float acc = hs1[8 * i + f];  // self-loop term
    for (int p = p0; p < p1; p++) {
        int s = srcsorted[p];
        acc += hs1[8 * s + f];
    }
    agg1[8 * i + f] = acc;
}

__global__ __launch_bounds__(256) void node2_kernel(
    const float* __restrict__ dinv, const float* __restrict__ agg1,
    const float* __restrict__ b1, const float* __restrict__ W2,
    float* __restrict__ hs2, int n) {
    int i = blockIdx.x * blockDim.x + threadIdx.x;
    if (i >= n) return;
    float d = dinv[i];
    const float4* ap = (const float4*)(agg1 + 8 * i);
    float4 a0 = ap[0], a1 = ap[1];
    float h[8];
    h[0] = fmaxf(d * a0.x + b1[0], 0.0f);
    h[1] = fmaxf(d * a0.y + b1[1], 0.0f);
    h[2] = fmaxf(d * a0.z + b1[2], 0.0f);
    h[3] = fmaxf(d * a0.w + b1[3], 0.0f);
    h[4] = fmaxf(d * a1.x + b1[4], 0.0f);
    h[5] = fmaxf(d * a1.y + b1[5], 0.0f);
    h[6] = fmaxf(d * a1.z + b1[6], 0.0f);
    h[7] = fmaxf(d * a1.w + b1[7], 0.0f);
    float oc[4];
    #pragma unroll
    for (int c = 0; c < 4; c++) {
        float acc = 0.0f;
        #pragma unroll
        for (int f = 0; f < 8; f++) acc += h[f] * W2[4 * f + c];
        oc[c] = acc * d;
    }
    float4 o;
    o.x = oc[0]; o.y = oc[1]; o.z = oc[2]; o.w = oc[3];
    *(float4*)(hs2 + 4 * i) = o;
}

// Thread = (node, feature f in 0..3); writes final output directly.
__global__ __launch_bounds__(256) void gather2_kernel(
    const int* __restrict__ rowptr, const int* __restrict__ cursor,
    const int* __restrict__ srcsorted, const float* __restrict__ hs2,
    const float* __restrict__ dinv, const float* __restrict__ b2,
    float* __restrict__ out, int n) {
    int t = blockIdx.x * blockDim.x + threadIdx.x;
    int i = t >> 2, f = t & 3;
    if (i >= n) return;
    int p0 = rowptr[i], p1 = cursor[i];
    float acc = hs2[4 * i + f];  // self-loop term
    for (int p = p0; p < p1; p++) {
        int s = srcsorted[p];
        acc += hs2[4 * s + f];
    }
    out[4 * i + f] = dinv[i] * acc + b2[f];
}

extern "C" void kernel_launch(void* const* d_in, const int* in_sizes, int n_in,
                              void* d_out, int out_size, void* d_ws, size_t ws_size,
                              hipStream_t stream) {
    const float* x   = (const float*)d_in[0];
    const int*   ei  = (const int*)d_in[1];
    const float* b1  = (const float*)d_in[3];
    const float* W1  = (const float*)d_in[2];
    const float* W2  = (const float*)d_in[4];
    const float* b2  = (const float*)d_in[5];
    float* out = (float*)d_out;

    const int n = in_sizes[0] / 2;  // x is [N,2]
    const int E = in_sizes[1] / 2;  // edge_index is [2,E]
    const int* src = ei;
    const int* dst = ei + E;

    char* wsb = (char*)d_ws;
    int*   deg       = (int*)wsb;                                   // n
    int*   rowptr    = deg + n;                                     // n+4
    int*   cursor    = rowptr + n + 4;                              // n
    int*   partials  = cursor + n;                                  // 256
    float* dinv      = (float*)(partials + 256);                    // n
    float* hs1       = dinv + n;                                    // 8n
    float* agg1      = hs1 + 8 * (size_t)n;                         // 8n
    float* hs2       = agg1 + 8 * (size_t)n;                        // 4n
    int*   srcsorted = (int*)(hs2 + 4 * (size_t)n);                 // E

    hipMemsetAsync(deg, 0, (size_t)n * sizeof(int), stream);

    const int TB = 256;
    const int gE = (E + TB - 1) / TB;
    const int gN = (n + TB - 1) / TB;
    const int NB = (n + 1023) / 1024;  // scan blocks (196)

    hist_kernel <<<gE, TB, 0, stream>>>(dst, deg, E);
    scan1_kernel<<<NB, TB, 0, stream>>>(deg, rowptr, partials, n);
    scan2_kernel<<<1,  TB, 0, stream>>>(partials, NB);
    scan3_kernel<<<gN, TB, 0, stream>>>(rowptr, cursor, partials, n, E);
    place_kernel<<<gE, TB, 0, stream>>>(src, dst, cursor, srcsorted, E);
    node1_kernel<<<gN, TB, 0, stream>>>(x, deg, dinv, W1, hs1, n);
    gather1_kernel<<<(8 * n + TB - 1) / TB, TB, 0, stream>>>(
        rowptr, cursor, srcsorted, hs1, agg1, n);
    node2_kernel<<<gN, TB, 0, stream>>>(dinv, agg1, b1, W2, hs2, n);
    gather2_kernel<<<(4 * n + TB - 1) / TB, TB, 0, stream>>>(
        rowptr, cursor, srcsorted, hs2, dinv, b2, out, n);
}

// Round 3
// 483.419 us; speedup vs baseline: 8.7281x; 2.2593x over previous
//
#include <hip/hip_runtime.h>

// GCN 2-layer on MI355X — Round 3: LDS-only bucket sort (no global atomics).
//
// agg[i] = dinv[i] * (sum_{e:dst=i} hs[src_e] + hs[i]),  hs[j] = (x@W)[j]*dinv[j]
//
// Sort: partition p = dst>>8 (256 nodes each). Per-block LDS histograms ->
// count matrix -> column scan -> packed bucket scatter -> per-partition LDS
// counting sort emitting rowptr + dst-sorted src list. deg comes free from
// rowptr diffs, so the old hist/deg pass is deleted.
//
// ws (4B words): rowptr[n+4] | colTotal[1024] | colStart[1028] | cntmat[B*P]
//   | packed[E]  (after part_sort, reused as dinv|hs1|agg1|hs2 = 4.2M words)
//   | srcsorted[E]                                   total ~53 MB

#define EPB 16384   // edges per block in bucket kernels
#define MAXP 1024   // >= P = ceil(n/256) = 782

__global__ __launch_bounds__(256) void bucket_count_kernel(
    const int* __restrict__ dst, int* __restrict__ cntmat, int E, int P) {
    __shared__ int cnt[MAXP];
    int tid = threadIdx.x;
    for (int p = tid; p < P; p += 256) cnt[p] = 0;
    __syncthreads();
    int base = blockIdx.x * EPB;
    for (int k = 0; k < EPB; k += 256) {
        int e = base + k + tid;
        if (e < E) atomicAdd(&cnt[dst[e] >> 8], 1);
    }
    __syncthreads();
    int* row = cntmat + (size_t)blockIdx.x * P;
    for (int p = tid; p < P; p += 256) row[p] = cnt[p];
}

// One block per partition column: exclusive scan of cnt[b][p] over b (in
// place), column total -> colTotal[p]. B <= 512.
__global__ __launch_bounds__(256) void col_scan_kernel(
    int* __restrict__ cntmat, int* __restrict__ colTotal, int B, int P) {
    __shared__ int sdata[256];
    int p = blockIdx.x, tid = threadIdx.x;
    int b0 = 2 * tid, b1 = 2 * tid + 1;
    int v0 = (b0 < B) ? cntmat[(size_t)b0 * P + p] : 0;
    int v1 = (b1 < B) ? cntmat[(size_t)b1 * P + p] : 0;
    int s = v0 + v1;
    int x = s;
    sdata[tid] = x;
    __syncthreads();
    for (int off = 1; off < 256; off <<= 1) {
        int t = (tid >= off) ? sdata[tid - off] : 0;
        __syncthreads();
        x += t;
        sdata[tid] = x;
        __syncthreads();
    }
    int run = x - s;
    if (b0 < B) cntmat[(size_t)b0 * P + p] = run;
    if (b1 < B) cntmat[(size_t)b1 * P + p] = run + v0;
    if (tid == 255) colTotal[p] = x;
}

// Single block: exclusive scan of colTotal[P] -> colStart[P+1]; sentinels.
__global__ __launch_bounds__(256) void total_scan_kernel(
    const int* __restrict__ colTotal, int* __restrict__ colStart,
    int* __restrict__ rowptr, int P, int n, int E) {
    __shared__ int sdata[256];
    int tid = threadIdx.x;
    int v[4];
    int s = 0;
    #pragma unroll
    for (int k = 0; k < 4; k++) {
        int i = tid * 4 + k;
        v[k] = (i < P) ? colTotal[i] : 0;
        s += v[k];
    }
    int x = s;
    sdata[tid] = x;
    __syncthreads();
    for (int off = 1; off < 256; off <<= 1) {
        int t = (tid >= off) ? sdata[tid - off] : 0;
        __syncthreads();
        x += t;
        sdata[tid] = x;
        __syncthreads();
    }
    int run = x - s;
    #pragma unroll
    for (int k = 0; k < 4; k++) {
        int i = tid * 4 + k;
        if (i < P) colStart[i] = run;
        run += v[k];
    }
    if (tid == 0) { colStart[P] = E; rowptr[n] = E; }
}

// Scatter edges into partition buckets via LDS cursors. packed = (ld<<18)|src
// (src < 2^18, localdst < 2^8).
__global__ __launch_bounds__(256) void bucket_scatter_kernel(
    const int* __restrict__ src, const int* __restrict__ dst,
    const int* __restrict__ cntmat, const int* __restrict__ colStart,
    unsigned* __restrict__ packed, int E, int P) {
    __shared__ int cur[MAXP];
    int tid = threadIdx.x;
    const int* row = cntmat + (size_t)blockIdx.x * P;
    for (int p = tid; p < P; p += 256) cur[p] = colStart[p] + row[p];
    __syncthreads();
    int base = blockIdx.x * EPB;
    for (int k = 0; k < EPB; k += 256) {
        int e = base + k + tid;
        if (e < E) {
            int d = dst[e];
            int pos = atomicAdd(&cur[d >> 8], 1);
            packed[pos] = ((unsigned)(d & 255) << 18) | (unsigned)src[e];
        }
    }
}

// One block per partition: LDS counting sort over localdst; emits rowptr and
// the dst-sorted src list. Second packed read is L2-hot.
__global__ __launch_bounds__(256) void part_sort_kernel(
    const unsigned* __restrict__ packed, const int* __restrict__ colStart,
    int* __restrict__ rowptr, int* __restrict__ srcsorted, int n) {
    __shared__ int hist[256];
    __shared__ int sdata[256];
    __shared__ int cur[256];
    int p = blockIdx.x, tid = threadIdx.x;
    int s0 = colStart[p], s1 = colStart[p + 1];
    hist[tid] = 0;
    __syncthreads();
    for (int i = s0 + tid; i < s1; i += 256)
        atomicAdd(&hist[packed[i] >> 18], 1);
    __syncthreads();
    int v = hist[tid];
    int x = v;
    sdata[tid] = x;
    __syncthreads();
    for (int off = 1; off < 256; off <<= 1) {
        int t = (tid >= off) ? sdata[tid - off] : 0;
        __syncthreads();
        x += t;
        sdata[tid] = x;
        __syncthreads();
    }
    int run = x - v;  // exclusive prefix over localdst
    int node = (p << 8) + tid;
    if (node < n) rowptr[node] = s0 + run;
    cur[tid] = s0 + run;
    __syncthreads();
    for (int i = s0 + tid; i < s1; i += 256) {
        unsigned w = packed[i];
        int pos = atomicAdd(&cur[w >> 18], 1);
        srcsorted[pos] = (int)(w & 0x3FFFFu);
    }
}

__global__ __launch_bounds__(256) void node1_kernel(
    const float* __restrict__ x, const int* __restrict__ rowptr,
    float* __restrict__ dinv, const float* __restrict__ W1,
    float* __restrict__ hs1, int n) {
    int i = blockIdx.x * blockDim.x + threadIdx.x;
    if (i >= n) return;
    int deg = rowptr[i + 1] - rowptr[i];
    float d = rsqrtf((float)deg + 1.0f);  // +1 for self-loop
    dinv[i] = d;
    float x0 = x[2 * i], x1 = x[2 * i + 1];
    float4 o0, o1;
    o0.x = (x0 * W1[0] + x1 * W1[8])  * d;
    o0.y = (x0 * W1[1] + x1 * W1[9])  * d;
    o0.z = (x0 * W1[2] + x1 * W1[10]) * d;
    o0.w = (x0 * W1[3] + x1 * W1[11]) * d;
    o1.x = (x0 * W1[4] + x1 * W1[12]) * d;
    o1.y = (x0 * W1[5] + x1 * W1[13]) * d;
    o1.z = (x0 * W1[6] + x1 * W1[14]) * d;
    o1.w = (x0 * W1[7] + x1 * W1[15]) * d;
    float4* outp = (float4*)(hs1 + 8 * i);
    outp[0] = o0;
    outp[1] = o1;
}

// Thread = (node, feature f in 0..7).
__global__ __launch_bounds__(256) void gather1_kernel(
    const int* __restrict__ rowptr, const int* __restrict__ srcsorted,
    const float* __restrict__ hs1, float* __restrict__ agg1, int n) {
    int t = blockIdx.x * blockDim.x + threadIdx.x;
    int i = t >> 3, f = t & 7;
    if (i >= n) return;
    int p0 = rowptr[i], p1 = rowptr[i + 1];
    float acc = hs1[8 * i + f];  // self-loop term
    for (int p = p0; p < p1; p++) {
        int s = srcsorted[p];
        acc += hs1[8 * s + f];
    }
    agg1[8 * i + f] = acc;
}

__global__ __launch_bounds__(256) void node2_kernel(
    const float* __restrict__ dinv, const float* __restrict__ agg1,
    const float* __restrict__ b1, const float* __restrict__ W2,
    float* __restrict__ hs2, int n) {
    int i = blockIdx.x * blockDim.x + threadIdx.x;
    if (i >= n) return;
    float d = dinv[i];
    const float4* ap = (const float4*)(agg1 + 8 * i);
    float4 a0 = ap[0], a1 = ap[1];
    float h[8];
    h[0] = fmaxf(d * a0.x + b1[0], 0.0f);
    h[1] = fmaxf(d * a0.y + b1[1], 0.0f);
    h[2] = fmaxf(d * a0.z + b1[2], 0.0f);
    h[3] = fmaxf(d * a0.w + b1[3], 0.0f);
    h[4] = fmaxf(d * a1.x + b1[4], 0.0f);
    h[5] = fmaxf(d * a1.y + b1[5], 0.0f);
    h[6] = fmaxf(d * a1.z + b1[6], 0.0f);
    h[7] = fmaxf(d * a1.w + b1[7], 0.0f);
    float oc[4];
    #pragma unroll
    for (int c = 0; c < 4; c++) {
        float acc = 0.0f;
        #pragma unroll
        for (int f = 0; f < 8; f++) acc += h[f] * W2[4 * f + c];
        oc[c] = acc * d;
    }
    float4 o;
    o.x = oc[0]; o.y = oc[1]; o.z = oc[2]; o.w = oc[3];
    *(float4*)(hs2 + 4 * i) = o;
}

// Thread = (node, feature f in 0..3); writes final output directly.
__global__ __launch_bounds__(256) void gather2_kernel(
    const int* __restrict__ rowptr, const int* __restrict__ srcsorted,
    const float* __restrict__ hs2, const float* __restrict__ dinv,
    const float* __restrict__ b2, float* __restrict__ out, int n) {
    int t = blockIdx.x * blockDim.x + threadIdx.x;
    int i = t >> 2, f = t & 3;
    if (i >= n) return;
    int p0 = rowptr[i], p1 = rowptr[i + 1];
    float acc = hs2[4 * i + f];  // self-loop term
    for (int p = p0; p < p1; p++) {
        int s = srcsorted[p];
        acc += hs2[4 * s + f];
    }
    out[4 * i + f] = dinv[i] * acc + b2[f];
}

extern "C" void kernel_launch(void* const* d_in, const int* in_sizes, int n_in,
                              void* d_out, int out_size, void* d_ws, size_t ws_size,
                              hipStream_t stream) {
    const float* x   = (const float*)d_in[0];
    const int*   ei  = (const int*)d_in[1];
    const float* W1  = (const float*)d_in[2];
    const float* b1  = (const float*)d_in[3];
    const float* W2  = (const float*)d_in[4];
    const float* b2  = (const float*)d_in[5];
    float* out = (float*)d_out;

    const int n = in_sizes[0] / 2;  // x is [N,2]
    const int E = in_sizes[1] / 2;  // edge_index is [2,E]
    const int* src = ei;
    const int* dst = ei + E;

    const int P = (n + 255) >> 8;          // 782 partitions of 256 nodes
    const int B = (E + EPB - 1) / EPB;     // 391 edge blocks

    int* ws = (int*)d_ws;
    int* rowptr   = ws;                                    // n+1 (pad n+4)
    int* colTotal = rowptr + n + 4;                        // pad 1024
    int* colStart = colTotal + 1024;                       // P+1 (pad 1028)
    int* cntmat   = colStart + 1028;                       // B*P
    size_t cm = ((size_t)B * P + 3) & ~(size_t)3;
    unsigned* packed = (unsigned*)(cntmat + cm);           // E words
    // packed region is dead after part_sort; reuse for node buffers:
    float* dinv = (float*)packed;                          // n
    float* hs1  = dinv + n;                                // 8n
    float* agg1 = hs1 + 8 * (size_t)n;                     // 8n
    float* hs2  = agg1 + 8 * (size_t)n;                    // 4n
    int* srcsorted = (int*)(packed + E);                   // E words

    const int TB = 256;
    const int gN = (n + TB - 1) / TB;

    bucket_count_kernel  <<<B, TB, 0, stream>>>(dst, cntmat, E, P);
    col_scan_kernel      <<<P, TB, 0, stream>>>(cntmat, colTotal, B, P);
    total_scan_kernel    <<<1, TB, 0, stream>>>(colTotal, colStart, rowptr, P, n, E);
    bucket_scatter_kernel<<<B, TB, 0, stream>>>(src, dst, cntmat, colStart, packed, E, P);
    part_sort_kernel     <<<P, TB, 0, stream>>>(packed, colStart, rowptr, srcsorted, n);
    node1_kernel         <<<gN, TB, 0, stream>>>(x, rowptr, dinv, W1, hs1, n);
    gather1_kernel       <<<(8 * n + TB - 1) / TB, TB, 0, stream>>>(rowptr, srcsorted, hs1, agg1, n);
    node2_kernel         <<<gN, TB, 0, stream>>>(dinv, agg1, b1, W2, hs2, n);
    gather2_kernel       <<<(4 * n + TB - 1) / TB, TB, 0, stream>>>(rowptr, srcsorted, hs2, dinv, b2, out, n);
}